// Round 1
// baseline (140.806 us; speedup 1.0000x reference)
//
#include <hip/hip_runtime.h>

#define N_BOND   100000
#define D_DIM    192
#define N_ETYPES 36
#define E_PER_TYPE 30000
#define BATCH    256
#define TOTAL_E  (N_ETYPES * E_PER_TYPE)

// Kernel 1: hv[n] = dot(h[n, :], W)   (one 64-lane wave per row; 48 lanes x float4 = 192 floats)
__global__ void hv_kernel(const float* __restrict__ h, const float* __restrict__ W,
                          float* __restrict__ hv) {
    int gwave = (blockIdx.x * blockDim.x + threadIdx.x) >> 6;
    int lane  = threadIdx.x & 63;
    if (gwave >= N_BOND) return;
    float v = 0.f;
    if (lane < 48) {
        const float4 a = ((const float4*)(h + (size_t)gwave * D_DIM))[lane];
        const float4 w = ((const float4*)W)[lane];
        v = a.x * w.x + a.y * w.y + a.z * w.z + a.w * w.w;
    }
#pragma unroll
    for (int d = 32; d > 0; d >>= 1) v += __shfl_down(v, d, 64);
    if (lane == 0) hv[gwave] = v;
}

// Kernel 2: scalar segment-sum over edges. key = t*BATCH + seg is globally
// non-decreasing (t grows with flat index, seg sorted within each type), so a
// wave-level segmented inclusive scan on sorted keys reduces 64 adds to ~2
// atomics per wave.
__global__ void edge_kernel(const int* __restrict__ edge_src,
                            const int* __restrict__ edge_seg,
                            const float* __restrict__ hv,
                            float* __restrict__ acc) {
    int e    = blockIdx.x * blockDim.x + threadIdx.x;
    int lane = threadIdx.x & 63;
    bool valid = (e < TOTAL_E);
    int ec  = valid ? e : (TOTAL_E - 1);   // clamp: invalid lanes join last segment with val=0
    int t   = ec / E_PER_TYPE;
    int seg = edge_seg[ec];
    int src = edge_src[ec];
    float val = valid ? hv[src] : 0.0f;
    int key = t * BATCH + seg;

    // segmented inclusive scan (keys sorted within the wave)
#pragma unroll
    for (int d = 1; d < 64; d <<= 1) {
        float uv = __shfl_up(val, d, 64);
        int   uk = __shfl_up(key, d, 64);
        if (lane >= d && uk == key) val += uv;
    }
    // last lane of each segment flushes the segment total
    int nk = __shfl_down(key, 1, 64);
    if (lane == 63 || nk != key) atomicAdd(&acc[key], val);
}

// Kernel 3: mask + softmax over the 36 types for each of 256 graphs.
// Thread b handles graph b; acc reads are coalesced (acc[t*BATCH + b]).
__global__ void softmax_kernel(const float* __restrict__ acc,
                               const void* __restrict__ mask,
                               float* __restrict__ out) {
    int b = threadIdx.x;  // 256 threads, 1 block

    // Detect mask storage width: bool(1B) vs int32(4B). For int32 storage every
    // word is exactly 0 or 1; for packed 0/1 bytes a word >1 appears with
    // overwhelming probability within 16 words.
    const unsigned int* mi = (const unsigned int*)mask;
    bool is_u8 = false;
#pragma unroll
    for (int i = 0; i < 16; ++i) is_u8 |= (mi[i] > 1u);
    const unsigned char* m8  = (const unsigned char*)mask;
    const int*           m32 = (const int*)mask;

    float v[N_ETYPES];
    float mx = -1e30f;
#pragma unroll
    for (int t = 0; t < N_ETYPES; ++t) {
        float x = acc[t * BATCH + b];
        bool masked = is_u8 ? (m8[b * N_ETYPES + t] != 0)
                            : (m32[b * N_ETYPES + t] != 0);
        x = masked ? -1e9f : x;
        v[t] = x;
        mx = fmaxf(mx, x);
    }
    float s = 0.f;
#pragma unroll
    for (int t = 0; t < N_ETYPES; ++t) { v[t] = expf(v[t] - mx); s += v[t]; }
    float inv = 1.f / s;
#pragma unroll
    for (int t = 0; t < N_ETYPES; ++t) out[b * N_ETYPES + t] = v[t] * inv;
}

extern "C" void kernel_launch(void* const* d_in, const int* in_sizes, int n_in,
                              void* d_out, int out_size, void* d_ws, size_t ws_size,
                              hipStream_t stream) {
    const float* h        = (const float*)d_in[0];   // [100000, 192]
    const float* W        = (const float*)d_in[1];   // [192, 1]
    const int*   edge_src = (const int*)d_in[2];     // [36, 30000]
    const int*   edge_seg = (const int*)d_in[3];     // [36, 30000]
    const void*  mask     = d_in[4];                 // [256, 36] bool (width auto-detected)
    float*       out      = (float*)d_out;           // [256, 36]

    float* hv  = (float*)d_ws;                              // 100000 floats
    float* acc = (float*)((char*)d_ws + 400128);            // 9216 floats, 128B-aligned

    hipMemsetAsync(acc, 0, N_ETYPES * BATCH * sizeof(float), stream);

    // 100000 rows, 4 waves (rows) per 256-thread block
    hipLaunchKernelGGL(hv_kernel, dim3((N_BOND + 3) / 4), dim3(256), 0, stream, h, W, hv);

    int eb = (TOTAL_E + 255) / 256;
    hipLaunchKernelGGL(edge_kernel, dim3(eb), dim3(256), 0, stream, edge_src, edge_seg, hv, acc);

    hipLaunchKernelGGL(softmax_kernel, dim3(1), dim3(256), 0, stream, acc, mask, out);
}